// Round 1
// baseline (3000.636 us; speedup 1.0000x reference)
//
#include <hip/hip_runtime.h>
#include <math.h>

// SDNConv: N nodes, K=8 factors, DK=16 dims. ROW = K*DK = 128 floats/node.
// f_out[n] = sum over concat slots of m_slot[n] @ W[:, slot*16:(slot+1)*16, :]
// Slots: 0=m_p_out, 1=m_p_in, 2=f_in(self), 3=m_n_out, 4=m_n_in
// Then tanh, then L2-normalize across K per (n, o).

#define ROW 128

__device__ __forceinline__ float dot16(float4 a0, float4 a1, float4 a2, float4 a3,
                                       const float* w) {
    return a0.x*w[0]  + a0.y*w[1]  + a0.z*w[2]  + a0.w*w[3]
         + a1.x*w[4]  + a1.y*w[5]  + a1.z*w[6]  + a1.w*w[7]
         + a2.x*w[8]  + a2.y*w[9]  + a2.z*w[10] + a2.w*w[11]
         + a3.x*w[12] + a3.y*w[13] + a3.z*w[14] + a3.w*w[15];
}

// One 128-thread group per edge; thread t=(k*16+o) computes output element (k,o)
// for both scatter directions of the edge. W sections held in registers,
// loop-invariant over the grid-stride edge loop.
__global__ __launch_bounds__(256) void scatter_kernel(
    const float* __restrict__ f_in,
    const int*   __restrict__ idx,    // (E,2) int32
    const float* __restrict__ W,      // (K, 80, 16)
    float*       __restrict__ out,    // (N, K, 16) accumulator
    int E, int rowA, int rowB)
{
    const int t = threadIdx.x & 127;
    const int k = t >> 4;
    const int o = t & 15;

    float wA[16], wB[16];
#pragma unroll
    for (int i = 0; i < 16; ++i) {
        wA[i] = W[k*1280 + (rowA + i)*16 + o];
        wB[i] = W[k*1280 + (rowB + i)*16 + o];
    }

    const int group  = blockIdx.x * 2 + (threadIdx.x >> 7);
    const int stride = gridDim.x * 2;

    for (int e = group; e < E; e += stride) {
        const int a = idx[2*e];
        const int b = idx[2*e + 1];

        // direction "out": f_in[b] scattered to node a through section rowA
        const float4* xb = (const float4*)(f_in + (size_t)b*ROW + k*16);
        // direction "in": f_in[a] scattered to node b through section rowB
        const float4* xa = (const float4*)(f_in + (size_t)a*ROW + k*16);

        float4 b0 = xb[0], b1 = xb[1], b2 = xb[2], b3 = xb[3];
        float4 a0 = xa[0], a1 = xa[1], a2 = xa[2], a3 = xa[3];

        float yA = dot16(b0, b1, b2, b3, wA);
        float yB = dot16(a0, a1, a2, a3, wB);

        unsafeAtomicAdd(out + (size_t)a*ROW + t, yA);
        unsafeAtomicAdd(out + (size_t)b*ROW + t, yB);
    }
}

// Per node: add self term (slot 2) + bias, tanh, L2-normalize across K.
// 2 nodes per 256-thread block; cross-K reduction via LDS.
__global__ __launch_bounds__(256) void finalize_kernel(
    const float* __restrict__ f_in,
    const float* __restrict__ W,
    const float* __restrict__ bias,   // (K,16) effectively
    float*       __restrict__ out,
    int N)
{
    __shared__ float sval[2][ROW];
    const int local = threadIdx.x >> 7;
    const int t = threadIdx.x & 127;
    const int k = t >> 4;
    const int o = t & 15;
    const int n = blockIdx.x * 2 + local;

    float w2[16];
#pragma unroll
    for (int i = 0; i < 16; ++i)
        w2[i] = W[k*1280 + (32 + i)*16 + o];

    float val = 0.0f;
    if (n < N) {
        const float4* xr = (const float4*)(f_in + (size_t)n*ROW + k*16);
        float4 x0 = xr[0], x1 = xr[1], x2 = xr[2], x3 = xr[3];
        float self = dot16(x0, x1, x2, x3, w2);
        float acc  = out[(size_t)n*ROW + t];
        val = tanhf(acc + self + bias[t]);
    }
    sval[local][t] = val;
    __syncthreads();

    if (n < N) {
        float ss = 0.0f;
#pragma unroll
        for (int k2 = 0; k2 < 8; ++k2) {
            float v = sval[local][k2*16 + o];
            ss += v * v;
        }
        float nrm = fmaxf(sqrtf(ss), 1e-12f);
        out[(size_t)n*ROW + t] = val / nrm;
    }
}

extern "C" void kernel_launch(void* const* d_in, const int* in_sizes, int n_in,
                              void* d_out, int out_size, void* d_ws, size_t ws_size,
                              hipStream_t stream) {
    const float* f_in = (const float*)d_in[0];
    const int*   Ep   = (const int*)d_in[1];
    const int*   En   = (const int*)d_in[2];
    const float* W    = (const float*)d_in[3];
    const float* b    = (const float*)d_in[4];
    float* out = (float*)d_out;

    const int N = in_sizes[0] / ROW;
    const int E = in_sizes[1] / 2;

    // d_out doubles as the f_out accumulator; zero it first.
    hipMemsetAsync(d_out, 0, (size_t)out_size * sizeof(float), stream);

    // Ep: slots 0 (rows 0..15) and 1 (rows 16..31)
    scatter_kernel<<<4096, 256, 0, stream>>>(f_in, Ep, W, out, E, 0, 16);
    // En: slots 3 (rows 48..63) and 4 (rows 64..79)
    scatter_kernel<<<4096, 256, 0, stream>>>(f_in, En, W, out, E, 48, 64);

    finalize_kernel<<<(N + 1) / 2, 256, 0, stream>>>(f_in, W, b, out, N);
}

// Round 2
// 1756.326 us; speedup vs baseline: 1.7085x; 1.7085x over previous
//
#include <hip/hip_runtime.h>
#include <math.h>

// SDNConv: N nodes, K=8 factors, DK=16 dims. ROW = K*DK = 128 floats/node.
// Strategy (R2): atomic-free. Build 4 CSRs (counts -> scan -> fill) in d_ws,
// then one fused PULL kernel: per-node segment-sums (plain adds), 80x16
// grouped matmul from LDS, tanh, cross-K L2-normalize, single write of out.
// Lists: 0 = Ep dst=a nb=b (W rows 0-15),  1 = Ep dst=b nb=a (rows 16-31),
//        self = rows 32-47,
//        2 = En dst=a nb=b (rows 48-63),  3 = En dst=b nb=a (rows 64-79).

#define ROW 128
#define SCAN_CHUNK 2048   // 256 threads x 8 elements

__device__ __forceinline__ float dot16(float4 a0, float4 a1, float4 a2, float4 a3,
                                       const float* w) {
    return a0.x*w[0]  + a0.y*w[1]  + a0.z*w[2]  + a0.w*w[3]
         + a1.x*w[4]  + a1.y*w[5]  + a1.z*w[6]  + a1.w*w[7]
         + a2.x*w[8]  + a2.y*w[9]  + a2.z*w[10] + a2.w*w[11]
         + a3.x*w[12] + a3.y*w[13] + a3.z*w[14] + a3.w*w[15];
}

__global__ __launch_bounds__(256) void count_kernel(
    const int* __restrict__ Ep, const int* __restrict__ En,
    int* __restrict__ C, int E, int N)
{
    int i = blockIdx.x * blockDim.x + threadIdx.x;
    int stride = gridDim.x * blockDim.x;
    for (int e = i; e < E; e += stride) {
        int a = Ep[2*e], b = Ep[2*e+1];
        atomicAdd(&C[a],         1);
        atomicAdd(&C[N + b],     1);
        int c = En[2*e], d = En[2*e+1];
        atomicAdd(&C[2*N + c],   1);
        atomicAdd(&C[3*N + d],   1);
    }
}

// Exclusive scan, 3-kernel hierarchy over M = 4N elements.
__global__ __launch_bounds__(256) void scan1_kernel(
    const int* __restrict__ C, int* __restrict__ O, int* __restrict__ BS, int M)
{
    __shared__ int sdata[256];
    const int tid = threadIdx.x;
    const int base = blockIdx.x * SCAN_CHUNK + tid * 8;
    int v[8]; int s = 0;
#pragma unroll
    for (int j = 0; j < 8; ++j) {
        int idx = base + j;
        v[j] = (idx < M) ? C[idx] : 0;
        s += v[j];
    }
    sdata[tid] = s;
    __syncthreads();
#pragma unroll
    for (int off = 1; off < 256; off <<= 1) {
        int x = (tid >= off) ? sdata[tid - off] : 0;
        __syncthreads();
        sdata[tid] += x;
        __syncthreads();
    }
    if (tid == 255) BS[blockIdx.x] = sdata[255];
    int run = sdata[tid] - s;   // exclusive prefix of this thread's chunk
#pragma unroll
    for (int j = 0; j < 8; ++j) {
        int idx = base + j;
        if (idx < M) O[idx] = run;
        run += v[j];
    }
}

__global__ __launch_bounds__(256) void scan2_kernel(int* __restrict__ BS, int n)
{
    __shared__ int sdata[256];
    const int tid = threadIdx.x;
    int v = (tid < n) ? BS[tid] : 0;
    sdata[tid] = v;
    __syncthreads();
#pragma unroll
    for (int off = 1; off < 256; off <<= 1) {
        int x = (tid >= off) ? sdata[tid - off] : 0;
        __syncthreads();
        sdata[tid] += x;
        __syncthreads();
    }
    if (tid < n) BS[tid] = sdata[tid] - v;   // exclusive
}

__global__ __launch_bounds__(256) void scan3_kernel(
    int* __restrict__ O, const int* __restrict__ BS, int M)
{
    const int add = BS[blockIdx.x];
    const int base = blockIdx.x * SCAN_CHUNK + threadIdx.x;
#pragma unroll
    for (int j = 0; j < 8; ++j) {
        int idx = base + j * 256;
        if (idx < M) O[idx] += add;
    }
}

// Fill CSR index lists; O acts as cursor array (ends up holding segment ENDs).
__global__ __launch_bounds__(256) void fill_kernel(
    const int* __restrict__ Ep, const int* __restrict__ En,
    int* __restrict__ O, int* __restrict__ idxbuf, int E, int N)
{
    int i = blockIdx.x * blockDim.x + threadIdx.x;
    int stride = gridDim.x * blockDim.x;
    for (int e = i; e < E; e += stride) {
        int a = Ep[2*e], b = Ep[2*e+1];
        idxbuf[atomicAdd(&O[a],       1)] = b;
        idxbuf[atomicAdd(&O[N + b],   1)] = a;
        int c = En[2*e], d = En[2*e+1];
        idxbuf[atomicAdd(&O[2*N + c], 1)] = d;
        idxbuf[atomicAdd(&O[3*N + d], 1)] = c;
    }
}

// Fused pull + grouped matmul + tanh + cross-K normalize.
// 128-thread group per node (2 nodes per 256-block), grid-stride over nodes.
__global__ __launch_bounds__(256) void pull_kernel(
    const float* __restrict__ f_in,
    const int*   __restrict__ C,      // counts per (list,node)
    const int*   __restrict__ O,      // segment ENDs per (list,node)
    const int*   __restrict__ idxbuf,
    const float* __restrict__ W,      // (K, 80, 16)
    const float* __restrict__ bias,
    float*       __restrict__ out,
    int N)
{
    __shared__ float sm[2][5][ROW];
    __shared__ float sa[2][ROW];
    const int local = threadIdx.x >> 7;
    const int t = threadIdx.x & 127;
    const int k = t >> 4;
    const int o = t & 15;

    // W rows for this (k,o): 80 floats, loop-invariant.
    float w[80];
#pragma unroll
    for (int i = 0; i < 80; ++i)
        w[i] = W[k*1280 + i*16 + o];
    const float bb = bias[t];

    for (int n0 = blockIdx.x * 2; n0 < N; n0 += gridDim.x * 2) {
        const int n = n0 + local;
        const bool act = (n < N);

        float accs[4] = {0.f, 0.f, 0.f, 0.f};
        float self = 0.f;
        if (act) {
#pragma unroll
            for (int l = 0; l < 4; ++l) {
                const int end = O[l*N + n];
                const int beg = end - C[l*N + n];
                float acc = 0.f;
                int j = beg;
                for (; j + 4 <= end; j += 4) {
                    int j0 = idxbuf[j],   j1 = idxbuf[j+1];
                    int j2 = idxbuf[j+2], j3 = idxbuf[j+3];
                    float x0 = f_in[(size_t)j0*ROW + t];
                    float x1 = f_in[(size_t)j1*ROW + t];
                    float x2 = f_in[(size_t)j2*ROW + t];
                    float x3 = f_in[(size_t)j3*ROW + t];
                    acc += x0 + x1 + x2 + x3;
                }
                for (; j < end; ++j)
                    acc += f_in[(size_t)idxbuf[j]*ROW + t];
                accs[l] = acc;
            }
            self = f_in[(size_t)n*ROW + t];
        }

        sm[local][0][t] = accs[0];   // m_p_out
        sm[local][1][t] = accs[1];   // m_p_in
        sm[local][2][t] = self;      // f_in
        sm[local][3][t] = accs[2];   // m_n_out
        sm[local][4][t] = accs[3];   // m_n_in
        __syncthreads();

        float y = bb;
#pragma unroll
        for (int s = 0; s < 5; ++s) {
            const float4* src = (const float4*)&sm[local][s][k*16];
            float4 v0 = src[0], v1 = src[1], v2 = src[2], v3 = src[3];
            y += dot16(v0, v1, v2, v3, &w[s*16]);
        }
        float a = tanhf(y);
        sa[local][t] = a;
        __syncthreads();

        float ss = 0.f;
#pragma unroll
        for (int k2 = 0; k2 < 8; ++k2) {
            float v = sa[local][k2*16 + o];
            ss += v * v;
        }
        if (act)
            out[(size_t)n*ROW + t] = a / fmaxf(sqrtf(ss), 1e-12f);
        __syncthreads();   // protect sm/sa before next iteration overwrites
    }
}

extern "C" void kernel_launch(void* const* d_in, const int* in_sizes, int n_in,
                              void* d_out, int out_size, void* d_ws, size_t ws_size,
                              hipStream_t stream) {
    const float* f_in = (const float*)d_in[0];
    const int*   Ep   = (const int*)d_in[1];
    const int*   En   = (const int*)d_in[2];
    const float* W    = (const float*)d_in[3];
    const float* b    = (const float*)d_in[4];
    float* out = (float*)d_out;

    const int N = in_sizes[0] / ROW;
    const int E = in_sizes[1] / 2;
    const int M = 4 * N;                       // total CSR segments
    const int nChunks = (M + SCAN_CHUNK - 1) / SCAN_CHUNK;   // 196 for N=100K

    // Workspace layout (~28.9 MB): C[4N] | O[4N] | BS[pad] | idxbuf[4E]
    int* C      = (int*)d_ws;
    int* O      = C + M;
    int* BS     = O + M;
    int* idxbuf = BS + ((nChunks + 255) & ~255);

    hipMemsetAsync(C, 0, (size_t)M * sizeof(int), stream);

    count_kernel<<<2048, 256, 0, stream>>>(Ep, En, C, E, N);
    scan1_kernel<<<nChunks, 256, 0, stream>>>(C, O, BS, M);
    scan2_kernel<<<1, 256, 0, stream>>>(BS, nChunks);
    scan3_kernel<<<nChunks, 256, 0, stream>>>(O, BS, M);
    fill_kernel<<<2048, 256, 0, stream>>>(Ep, En, O, idxbuf, E, N);

    pull_kernel<<<4096, 256, 0, stream>>>(f_in, C, O, idxbuf, W, b, out, N);
}

// Round 3
// 1545.691 us; speedup vs baseline: 1.9413x; 1.1363x over previous
//
#include <hip/hip_runtime.h>
#include <math.h>

// SDNConv: N nodes, K=8 factors, DK=16. ROW = 128 floats/node.
// R3: atomic-free CSR pull. Pull kernel uses 256 threads per node so each
// thread holds only 40 weights in registers (no scratch spill); the two
// 128-thread halves split the neighbor lists (2x gather MLP) and combine
// partial dot-products through LDS.
// Lists: 0 = Ep dst=a nb=b (W rows 0-15),  1 = Ep dst=b nb=a (rows 16-31),
//        self = rows 32-47,
//        2 = En dst=a nb=b (rows 48-63),  3 = En dst=b nb=a (rows 64-79).

#define ROW 128
#define SCAN_CHUNK 2048   // 256 threads x 8 elements

__global__ __launch_bounds__(256) void count_kernel(
    const int4* __restrict__ Ep2, const int4* __restrict__ En2,
    const int* __restrict__ Ep, const int* __restrict__ En,
    int* __restrict__ C, int Epairs, int Etail, int N)
{
    int i = blockIdx.x * 256 + threadIdx.x;
    int stride = gridDim.x * 256;
    for (int e = i; e < Epairs; e += stride) {
        int4 p = Ep2[e];
        atomicAdd(&C[p.x],       1);
        atomicAdd(&C[N + p.y],   1);
        atomicAdd(&C[p.z],       1);
        atomicAdd(&C[N + p.w],   1);
        int4 q = En2[e];
        atomicAdd(&C[2*N + q.x], 1);
        atomicAdd(&C[3*N + q.y], 1);
        atomicAdd(&C[2*N + q.z], 1);
        atomicAdd(&C[3*N + q.w], 1);
    }
    if (i == 0 && Etail) {   // odd E tail edge
        int e = 2 * Epairs;
        atomicAdd(&C[Ep[2*e]],         1);
        atomicAdd(&C[N + Ep[2*e+1]],   1);
        atomicAdd(&C[2*N + En[2*e]],   1);
        atomicAdd(&C[3*N + En[2*e+1]], 1);
    }
}

__global__ __launch_bounds__(256) void scan1_kernel(
    const int* __restrict__ C, int* __restrict__ O, int* __restrict__ BS, int M)
{
    __shared__ int sdata[256];
    const int tid = threadIdx.x;
    const int base = blockIdx.x * SCAN_CHUNK + tid * 8;
    int v[8]; int s = 0;
#pragma unroll
    for (int j = 0; j < 8; ++j) {
        int idx = base + j;
        v[j] = (idx < M) ? C[idx] : 0;
        s += v[j];
    }
    sdata[tid] = s;
    __syncthreads();
#pragma unroll
    for (int off = 1; off < 256; off <<= 1) {
        int x = (tid >= off) ? sdata[tid - off] : 0;
        __syncthreads();
        sdata[tid] += x;
        __syncthreads();
    }
    if (tid == 255) BS[blockIdx.x] = sdata[255];
    int run = sdata[tid] - s;
#pragma unroll
    for (int j = 0; j < 8; ++j) {
        int idx = base + j;
        if (idx < M) O[idx] = run;
        run += v[j];
    }
}

__global__ __launch_bounds__(256) void scan2_kernel(int* __restrict__ BS, int n)
{
    __shared__ int sdata[256];
    const int tid = threadIdx.x;
    int v = (tid < n) ? BS[tid] : 0;
    sdata[tid] = v;
    __syncthreads();
#pragma unroll
    for (int off = 1; off < 256; off <<= 1) {
        int x = (tid >= off) ? sdata[tid - off] : 0;
        __syncthreads();
        sdata[tid] += x;
        __syncthreads();
    }
    if (tid < n) BS[tid] = sdata[tid] - v;
}

__global__ __launch_bounds__(256) void scan3_kernel(
    int* __restrict__ O, const int* __restrict__ BS, int M)
{
    const int add = BS[blockIdx.x];
    const int base = blockIdx.x * SCAN_CHUNK + threadIdx.x;
#pragma unroll
    for (int j = 0; j < 8; ++j) {
        int idx = base + j * 256;
        if (idx < M) O[idx] += add;
    }
}

__global__ __launch_bounds__(256) void fill_kernel(
    const int4* __restrict__ Ep2, const int4* __restrict__ En2,
    const int* __restrict__ Ep, const int* __restrict__ En,
    int* __restrict__ O, int* __restrict__ idxbuf, int Epairs, int Etail, int N)
{
    int i = blockIdx.x * 256 + threadIdx.x;
    int stride = gridDim.x * 256;
    for (int e = i; e < Epairs; e += stride) {
        int4 p = Ep2[e];
        idxbuf[atomicAdd(&O[p.x],       1)] = p.y;
        idxbuf[atomicAdd(&O[N + p.y],   1)] = p.x;
        idxbuf[atomicAdd(&O[p.z],       1)] = p.w;
        idxbuf[atomicAdd(&O[N + p.w],   1)] = p.z;
        int4 q = En2[e];
        idxbuf[atomicAdd(&O[2*N + q.x], 1)] = q.y;
        idxbuf[atomicAdd(&O[3*N + q.y], 1)] = q.x;
        idxbuf[atomicAdd(&O[2*N + q.z], 1)] = q.w;
        idxbuf[atomicAdd(&O[3*N + q.w], 1)] = q.z;
    }
    if (i == 0 && Etail) {
        int e = 2 * Epairs;
        int a = Ep[2*e], b = Ep[2*e+1];
        idxbuf[atomicAdd(&O[a],       1)] = b;
        idxbuf[atomicAdd(&O[N + b],   1)] = a;
        int c = En[2*e], d = En[2*e+1];
        idxbuf[atomicAdd(&O[2*N + c], 1)] = d;
        idxbuf[atomicAdd(&O[3*N + d], 1)] = c;
    }
}

// 256 threads per node: elem = tid&127 picks the (k,o) output element,
// h = tid>>7 picks which half of the 80-row W-column / neighbor list this
// thread covers. 40 weights per thread stay in registers.
__global__ __launch_bounds__(256, 4) void pull_kernel(
    const float* __restrict__ f_in,
    const int*   __restrict__ C,
    const int*   __restrict__ O,      // segment ENDs
    const int*   __restrict__ idxbuf,
    const float* __restrict__ W,      // (K, 80, 16)
    const float* __restrict__ bias,
    float*       __restrict__ out,
    int N)
{
    __shared__ float sacc[2][5][ROW];
    __shared__ float syp[2][ROW];
    __shared__ float sa[ROW];

    const int tid  = threadIdx.x;
    const int elem = tid & 127;
    const int h    = tid >> 7;
    const int k    = elem >> 4;
    const int o    = elem & 15;

    float w[5][8];
#pragma unroll
    for (int s = 0; s < 5; ++s)
#pragma unroll
        for (int i = 0; i < 8; ++i)
            w[s][i] = W[k*1280 + (s*16 + h*8 + i)*16 + o];
    const float bb = bias[elem];

    for (int n = blockIdx.x; n < N; n += gridDim.x) {
#pragma unroll
        for (int l = 0; l < 4; ++l) {
            const int end = O[l*N + n];
            const int beg = end - C[l*N + n];
            float acc = 0.f;
            int j = beg + h;
            for (; j + 6 < end; j += 8) {       // 4 gathers in flight
                int j0 = idxbuf[j],   j1 = idxbuf[j+2];
                int j2 = idxbuf[j+4], j3 = idxbuf[j+6];
                float x0 = f_in[(size_t)j0*ROW + elem];
                float x1 = f_in[(size_t)j1*ROW + elem];
                float x2 = f_in[(size_t)j2*ROW + elem];
                float x3 = f_in[(size_t)j3*ROW + elem];
                acc += x0 + x1 + x2 + x3;
            }
            for (; j < end; j += 2)
                acc += f_in[(size_t)idxbuf[j]*ROW + elem];
            const int s = (l < 2) ? l : l + 1;  // slots 0,1,3,4
            sacc[h][s][elem] = acc;
        }
        sacc[h][2][elem] = h ? 0.f : f_in[(size_t)n*ROW + elem];
        __syncthreads();

        float y = 0.f;
#pragma unroll
        for (int s = 0; s < 5; ++s) {
            const float* m0 = &sacc[0][s][k*16 + h*8];
            const float* m1 = &sacc[1][s][k*16 + h*8];
#pragma unroll
            for (int i = 0; i < 8; ++i)
                y += (m0[i] + m1[i]) * w[s][i];
        }
        syp[h][elem] = y;
        __syncthreads();

        float a = 0.f;
        if (h == 0) {
            a = tanhf(syp[0][elem] + syp[1][elem] + bb);
            sa[elem] = a;
        }
        __syncthreads();
        if (h == 0) {
            float ss = 0.f;
#pragma unroll
            for (int k2 = 0; k2 < 8; ++k2) {
                float v = sa[k2*16 + o];
                ss += v * v;
            }
            out[(size_t)n*ROW + elem] = a / fmaxf(sqrtf(ss), 1e-12f);
        }
        __syncthreads();   // protect LDS before next node iteration
    }
}

extern "C" void kernel_launch(void* const* d_in, const int* in_sizes, int n_in,
                              void* d_out, int out_size, void* d_ws, size_t ws_size,
                              hipStream_t stream) {
    const float* f_in = (const float*)d_in[0];
    const int*   Ep   = (const int*)d_in[1];
    const int*   En   = (const int*)d_in[2];
    const float* W    = (const float*)d_in[3];
    const float* b    = (const float*)d_in[4];
    float* out = (float*)d_out;

    const int N = in_sizes[0] / ROW;
    const int E = in_sizes[1] / 2;
    const int Epairs = E / 2;
    const int Etail  = E & 1;
    const int M = 4 * N;
    const int nChunks = (M + SCAN_CHUNK - 1) / SCAN_CHUNK;

    int* C      = (int*)d_ws;
    int* O      = C + M;
    int* BS     = O + M;
    int* idxbuf = BS + ((nChunks + 255) & ~255);

    hipMemsetAsync(C, 0, (size_t)M * sizeof(int), stream);

    count_kernel<<<1024, 256, 0, stream>>>((const int4*)Ep, (const int4*)En,
                                           Ep, En, C, Epairs, Etail, N);
    scan1_kernel<<<nChunks, 256, 0, stream>>>(C, O, BS, M);
    scan2_kernel<<<1, 256, 0, stream>>>(BS, nChunks);
    scan3_kernel<<<nChunks, 256, 0, stream>>>(O, BS, M);
    fill_kernel<<<2048, 256, 0, stream>>>((const int4*)Ep, (const int4*)En,
                                          Ep, En, O, idxbuf, Epairs, Etail, N);

    pull_kernel<<<8192, 256, 0, stream>>>(f_in, C, O, idxbuf, W, b, out, N);
}